// Round 13
// baseline (321.098 us; speedup 1.0000x reference)
//
#include <hip/hip_runtime.h>
#include <math.h>

namespace {

constexpr int TSTEPS = 512;
constexpr int F_IN   = 25;
constexpr int H_DIM  = 64;
constexpr int TILE_B = 16;
constexpr int NTHR   = 256;
// K-split: x-slice (x(25) | fused bias | pad) lives entirely in registers --
// loads ISSUED at step top, CONSUMED (cvt + 4 x-MFMAs -> accx) at step END,
// after the h-write and before __syncthreads (vmcnt=0 at barrier -> drain
// free; R8 pinned this rule). h: 2 K-slices in LDS as A-fragments,
// double-buffered: h_buf[dbuf][slice][lane][j], lane = row + 16*(k'>>3),
// j = k'&7, k' = unit & 31, slice = unit >> 5. Mapping validated in R7.

typedef __attribute__((ext_vector_type(8))) short bf16x8;
typedef __attribute__((ext_vector_type(4))) float f32x4;

constexpr float LOG2E  = 1.4426950408889634f;
constexpr float LOG2E2 = 2.8853900817779268f;

__device__ __forceinline__ short f2bf(float f) {  // RNE (setup only)
    unsigned u = __float_as_uint(f);
    unsigned r = (u + 0x7FFFu + ((u >> 16) & 1u)) >> 16;
    return (short)r;
}
__device__ __forceinline__ unsigned cvt_pk_bf16(float lo, float hi) {
    unsigned r;
    asm("v_cvt_pk_bf16_f32 %0, %1, %2" : "=v"(r) : "v"(lo), "v"(hi));
    return r;
}
__device__ __forceinline__ float exp2_neg(float x) {      // 2^(-x)
    float r;
    asm("v_exp_f32 %0, -%1" : "=v"(r) : "v"(x));
    return r;
}
__device__ __forceinline__ float exp2_negabs(float x) {   // 2^(-|x|)
    float r;
    asm("v_exp_f32 %0, -abs(%1)" : "=v"(r) : "v"(x));
    return r;
}
// 4-way reciprocal with ONE v_rcp (product inverse). All a_q >= 1; overflow
// needs sum|z'| > ~120 -- impossible here. Validated R7/R8/R10/R12.
__device__ __forceinline__ void inv4(float a0, float a1, float a2, float a3,
                                     float& i0, float& i1, float& i2, float& i3) {
    const float s01 = a0 * a1;
    const float s23 = a2 * a3;
    const float rp  = __builtin_amdgcn_rcpf(s01 * s23);
    const float t01 = rp * s23;
    const float t23 = rp * s01;
    i0 = t01 * a1;
    i1 = t01 * a0;
    i2 = t23 * a3;
    i3 = t23 * a2;
}

__global__ __launch_bounds__(NTHR)
void lstm_mfma(const float* __restrict__ x,     // [B, T, F]
               const float* __restrict__ Wx_w,  // [256, 25]
               const float* __restrict__ Wx_b,  // [256]
               const float* __restrict__ Wh_w,  // [256, 64]
               const float* __restrict__ Wh_b,  // [256]
               const float* __restrict__ fc_w,  // [64]
               const float* __restrict__ fc_b,  // [1]
               float* __restrict__ out)         // [B]
{
    __shared__ short h_buf[2][2][64][8];   // 4096 B
    __shared__ float red[4][16];

    const int tid  = threadIdx.x;
    const int l    = tid & 63;
    const int wv   = tid >> 6;       // wave: units [wv*16, wv*16+16) x 4 gates
    const int lrow = l & 15;
    const int lhi  = l >> 4;
    const int row0 = blockIdx.x * TILE_B;

    // ---- weights: x-slice (w_x) + 2 h-slices (w_h), log2e pre-scaled ----
    bf16x8 w_x[4], w_h[4][2];
    #pragma unroll
    for (int g = 0; g < 4; ++g) {
        const int col = g * 64 + wv * 16 + lrow;
        const float scale = (g == 2) ? LOG2E2 : LOG2E;   // gates i,f,g,o
        #pragma unroll
        for (int j = 0; j < 8; ++j) {
            const int k = lhi * 8 + j;
            float val;
            if (k < F_IN)       val = Wx_w[col * F_IN + k];
            else if (k == F_IN) val = Wx_b[col] + Wh_b[col];   // fused bias
            else                val = 0.0f;
            w_x[g][j] = f2bf(val * scale);
        }
        #pragma unroll
        for (int s = 0; s < 2; ++s) {
            #pragma unroll
            for (int j = 0; j < 8; ++j) {
                const int u = s * 32 + lhi * 8 + j;
                w_h[g][s][j] = f2bf(Wh_w[col * H_DIM + u] * scale);
            }
        }
    }

    // ---- init h_buf = 0 (h0 = 0), both buffers ----
    for (int idx = tid; idx < 2 * 2 * 64 * 8; idx += NTHR)
        ((short*)h_buf)[idx] = 0;
    __syncthreads();

    const float* xrow = x + (size_t)(row0 + lrow) * TSTEPS * F_IN;
    const f32x4 czero = {0.f, 0.f, 0.f, 0.f};

    // ---- prologue: acc_x for t=0 (direct build from x(0)) ----
    f32x4 accx0, accx1, accx2, accx3;
    {
        union { unsigned u[4]; bf16x8 v; } xr;
        if (lhi < 3) {
            float tmp[8];
            __builtin_memcpy(tmp, xrow + lhi * 8, 32);
            xr.u[0] = cvt_pk_bf16(tmp[0], tmp[1]);
            xr.u[1] = cvt_pk_bf16(tmp[2], tmp[3]);
            xr.u[2] = cvt_pk_bf16(tmp[4], tmp[5]);
            xr.u[3] = cvt_pk_bf16(tmp[6], tmp[7]);
        } else {
            xr.u[0] = cvt_pk_bf16(xrow[24], 1.0f);
            xr.u[1] = 0; xr.u[2] = 0; xr.u[3] = 0;
        }
        accx0 = __builtin_amdgcn_mfma_f32_16x16x32_bf16(xr.v, w_x[0], czero, 0, 0, 0);
        accx1 = __builtin_amdgcn_mfma_f32_16x16x32_bf16(xr.v, w_x[1], czero, 0, 0, 0);
        accx2 = __builtin_amdgcn_mfma_f32_16x16x32_bf16(xr.v, w_x[2], czero, 0, 0, 0);
        accx3 = __builtin_amdgcn_mfma_f32_16x16x32_bf16(xr.v, w_x[3], czero, 0, 0, 0);
    }

    // ---- h-write slot: unit -> slice unit>>5, lane bank ((unit&31)>>3)<<4 ----
    const int unit = wv * 16 + lrow;
    const int sh   = unit >> 5;
    const int bank = ((unit & 31) >> 3) << 4;
    const int jh   = unit & 7;

    const float fcw = fc_w[unit];
    float c[4]  = {0.f, 0.f, 0.f, 0.f};
    float hq[4] = {0.f, 0.f, 0.f, 0.f};
    float xl[8];

    // One step; DO_X folds at compile time (true for all but the last step).
    // Order: issue x loads -> h ds_read -> 8 h-MFMAs -> cells -> h-write ->
    // x consume (cvt + 4 x-MFMAs) -> __syncthreads (vmcnt already 0).
    auto step = [&](int t, bool DO_X) {
        const int p  = t & 1;
        const int pn = p ^ 1;

        // 1) issue x(t+1) loads (full step of cover before consumption)
        if (DO_X) {
            const float* px = xrow + (t + 1) * F_IN;
            if (lhi < 3) __builtin_memcpy(xl, px + lhi * 8, 32);
            else         xl[0] = px[24];
        }

        // 2) h fragments (2 slices, broadcast b128, conflict-free)
        const bf16x8 h1 = *(const bf16x8*)&h_buf[p][0][l][0];
        const bf16x8 h2 = *(const bf16x8*)&h_buf[p][1][l][0];

        // 3) z' = accx + h @ Wh'^T : 8 MFMAs on the post-barrier chain
        f32x4 acc0, acc1, acc2, acc3;
        acc0 = __builtin_amdgcn_mfma_f32_16x16x32_bf16(h1, w_h[0][0], accx0, 0, 0, 0);
        acc1 = __builtin_amdgcn_mfma_f32_16x16x32_bf16(h1, w_h[1][0], accx1, 0, 0, 0);
        acc2 = __builtin_amdgcn_mfma_f32_16x16x32_bf16(h1, w_h[2][0], accx2, 0, 0, 0);
        acc3 = __builtin_amdgcn_mfma_f32_16x16x32_bf16(h1, w_h[3][0], accx3, 0, 0, 0);
        acc0 = __builtin_amdgcn_mfma_f32_16x16x32_bf16(h2, w_h[0][1], acc0, 0, 0, 0);
        acc1 = __builtin_amdgcn_mfma_f32_16x16x32_bf16(h2, w_h[1][1], acc1, 0, 0, 0);
        acc2 = __builtin_amdgcn_mfma_f32_16x16x32_bf16(h2, w_h[2][1], acc2, 0, 0, 0);
        acc3 = __builtin_amdgcn_mfma_f32_16x16x32_bf16(h2, w_h[3][1], acc3, 0, 0, 0);

        // 4) 4 cells; 20 exp + 3 batched rcp per thread
        const float ei0 = exp2_neg(acc0[0]), ei1 = exp2_neg(acc0[1]),
                    ei2 = exp2_neg(acc0[2]), ei3 = exp2_neg(acc0[3]);
        const float ef0 = exp2_neg(acc1[0]), ef1 = exp2_neg(acc1[1]),
                    ef2 = exp2_neg(acc1[2]), ef3 = exp2_neg(acc1[3]);
        const float eg0 = exp2_negabs(acc2[0]), eg1 = exp2_negabs(acc2[1]),
                    eg2 = exp2_negabs(acc2[2]), eg3 = exp2_negabs(acc2[3]);
        const float eo0 = exp2_neg(acc3[0]), eo1 = exp2_neg(acc3[1]),
                    eo2 = exp2_neg(acc3[2]), eo3 = exp2_neg(acc3[3]);

        const float A0 = (1.f + ei0) * (1.f + eg0), A1 = (1.f + ei1) * (1.f + eg1),
                    A2 = (1.f + ei2) * (1.f + eg2), A3 = (1.f + ei3) * (1.f + eg3);
        float iA0, iA1, iA2, iA3;
        inv4(A0, A1, A2, A3, iA0, iA1, iA2, iA3);
        float f0, f1, f2, f3;
        inv4(1.f + ef0, 1.f + ef1, 1.f + ef2, 1.f + ef3, f0, f1, f2, f3);

        const float ig0 = copysignf((1.f - eg0) * iA0, acc2[0]);
        const float ig1 = copysignf((1.f - eg1) * iA1, acc2[1]);
        const float ig2 = copysignf((1.f - eg2) * iA2, acc2[2]);
        const float ig3 = copysignf((1.f - eg3) * iA3, acc2[3]);

        const float cn0 = fmaf(c[0], f0, ig0);
        const float cn1 = fmaf(c[1], f1, ig1);
        const float cn2 = fmaf(c[2], f2, ig2);
        const float cn3 = fmaf(c[3], f3, ig3);
        c[0] = cn0; c[1] = cn1; c[2] = cn2; c[3] = cn3;

        const float ec0 = exp2_negabs(cn0 * LOG2E2);
        const float ec1 = exp2_negabs(cn1 * LOG2E2);
        const float ec2 = exp2_negabs(cn2 * LOG2E2);
        const float ec3 = exp2_negabs(cn3 * LOG2E2);
        const float C0 = (1.f + eo0) * (1.f + ec0), C1 = (1.f + eo1) * (1.f + ec1),
                    C2 = (1.f + eo2) * (1.f + ec2), C3 = (1.f + eo3) * (1.f + ec3);
        float iC0, iC1, iC2, iC3;
        inv4(C0, C1, C2, C3, iC0, iC1, iC2, iC3);

        const float h0  = copysignf((1.f - ec0) * iC0, cn0);
        const float h1v = copysignf((1.f - ec1) * iC1, cn1);
        const float h2v = copysignf((1.f - ec2) * iC2, cn2);
        const float h3v = copysignf((1.f - ec3) * iC3, cn3);
        hq[0] = h0; hq[1] = h1v; hq[2] = h2v; hq[3] = h3v;

        // 5) h -> h_buf[pn] (packed cvt, strided b16 stores; R7-validated map)
        const unsigned u01 = cvt_pk_bf16(h0, h1v);
        const unsigned u23 = cvt_pk_bf16(h2v, h3v);
        short* const hdst = &h_buf[pn][sh][0][0] + (bank + lhi * 4) * 8 + jh;
        hdst[0]  = (short)(u01 & 0xffffu);
        hdst[8]  = (short)(u01 >> 16);
        hdst[16] = (short)(u23 & 0xffffu);
        hdst[24] = (short)(u23 >> 16);

        // 6) consume x(t+1): cvt + 4 x-MFMAs -> accx for next step (off the
        //    post-barrier chain; fills the matrix-pipe idle / barrier skew)
        if (DO_X) {
            union { unsigned u[4]; bf16x8 v; } xr;
            if (lhi < 3) {
                xr.u[0] = cvt_pk_bf16(xl[0], xl[1]);
                xr.u[1] = cvt_pk_bf16(xl[2], xl[3]);
                xr.u[2] = cvt_pk_bf16(xl[4], xl[5]);
                xr.u[3] = cvt_pk_bf16(xl[6], xl[7]);
            } else {
                xr.u[0] = cvt_pk_bf16(xl[0], 1.0f);
                xr.u[1] = 0; xr.u[2] = 0; xr.u[3] = 0;
            }
            accx0 = __builtin_amdgcn_mfma_f32_16x16x32_bf16(xr.v, w_x[0], czero, 0, 0, 0);
            accx1 = __builtin_amdgcn_mfma_f32_16x16x32_bf16(xr.v, w_x[1], czero, 0, 0, 0);
            accx2 = __builtin_amdgcn_mfma_f32_16x16x32_bf16(xr.v, w_x[2], czero, 0, 0, 0);
            accx3 = __builtin_amdgcn_mfma_f32_16x16x32_bf16(xr.v, w_x[3], czero, 0, 0, 0);
        }

        // 7) full barrier (+ memory fences -- the IR-sound version; vmcnt is
        //    already 0 here so the drain costs nothing)
        __syncthreads();
    };

    // steady state branchless (DO_X folds true), last step peeled
    for (int t = 0; t < TSTEPS - 1; ++t) step(t, true);
    step(TSTEPS - 1, false);

    // ---- epilogue: logits = h_last @ fc_w + fc_b ----
    #pragma unroll
    for (int q = 0; q < 4; ++q) {
        float pq = hq[q] * fcw;
        pq += __shfl_xor(pq, 1);
        pq += __shfl_xor(pq, 2);
        pq += __shfl_xor(pq, 4);
        pq += __shfl_xor(pq, 8);
        if (lrow == 0) red[wv][lhi * 4 + q] = pq;
    }
    __syncthreads();
    if (tid < TILE_B) {
        out[row0 + tid] = red[0][tid] + red[1][tid] + red[2][tid] + red[3][tid] + fc_b[0];
    }
}

} // namespace

extern "C" void kernel_launch(void* const* d_in, const int* in_sizes, int n_in,
                              void* d_out, int out_size, void* d_ws, size_t ws_size,
                              hipStream_t stream) {
    const float* x    = (const float*)d_in[0];
    // d_in[1] = mask: all-ones, use_masked_last=False -> unused
    const float* Wx_w = (const float*)d_in[2];
    const float* Wx_b = (const float*)d_in[3];
    const float* Wh_w = (const float*)d_in[4];
    const float* Wh_b = (const float*)d_in[5];
    const float* fc_w = (const float*)d_in[6];
    const float* fc_b = (const float*)d_in[7];
    float* out = (float*)d_out;

    const int B    = out_size;        // 4096
    const int grid = B / TILE_B;      // 256 blocks = 1 per CU

    lstm_mfma<<<grid, NTHR, 0, stream>>>(x, Wx_w, Wx_b, Wh_w, Wh_b, fc_w, fc_b, out);
}

// Round 14
// 242.702 us; speedup vs baseline: 1.3230x; 1.3230x over previous
//
#include <hip/hip_runtime.h>
#include <math.h>

namespace {

constexpr int TSTEPS = 512;
constexpr int F_IN   = 25;
constexpr int H_DIM  = 64;
constexpr int TILE_B = 16;
constexpr int NTHR   = 256;
// K layout: [0,25) = x, [25,89) = h, 89 = bias-one, [90,96) = zero pad
// A-fragment buffer: [2 bufs][3 ksteps][64 lanes][8 bf16], fragment-ordered:
//   slot (s, lane, j) holds A[row = lane&15][k = s*32 + (lane>>4)*8 + j]

typedef __attribute__((ext_vector_type(8))) short bf16x8;
typedef __attribute__((ext_vector_type(4))) float f32x4;

constexpr float LOG2E  = 1.4426950408889634f;
constexpr float LOG2E2 = 2.8853900817779268f;

__device__ __forceinline__ short f2bf(float f) {  // RNE (setup only)
    unsigned u = __float_as_uint(f);
    unsigned r = (u + 0x7FFFu + ((u >> 16) & 1u)) >> 16;
    return (short)r;
}
__device__ __forceinline__ unsigned cvt_pk_bf16(float lo, float hi) {
    unsigned r;
    asm("v_cvt_pk_bf16_f32 %0, %1, %2" : "=v"(r) : "v"(lo), "v"(hi));
    return r;
}
__device__ __forceinline__ float exp2_neg(float x) {      // 2^(-x)
    float r;
    asm("v_exp_f32 %0, -%1" : "=v"(r) : "v"(x));
    return r;
}
__device__ __forceinline__ float exp2_negabs(float x) {   // 2^(-|x|)
    float r;
    asm("v_exp_f32 %0, -abs(%1)" : "=v"(r) : "v"(x));
    return r;
}
// 4-way reciprocal with ONE v_rcp (product inverse). All a_q >= 1; overflow
// needs sum of exponents > 127 (sum|z'| > ~120) -- impossible here.
// Validated R7/R8/R10/R12: absmax identical to per-cell rcp.
__device__ __forceinline__ void inv4(float a0, float a1, float a2, float a3,
                                     float& i0, float& i1, float& i2, float& i3) {
    const float s01 = a0 * a1;
    const float s23 = a2 * a3;
    const float rp  = __builtin_amdgcn_rcpf(s01 * s23);
    const float t01 = rp * s23;
    const float t23 = rp * s01;
    i0 = t01 * a1;
    i1 = t01 * a0;
    i2 = t23 * a3;
    i3 = t23 * a2;
}

__global__ __launch_bounds__(NTHR)
void lstm_mfma(const float* __restrict__ x,     // [B, T, F]
               const float* __restrict__ Wx_w,  // [256, 25]
               const float* __restrict__ Wx_b,  // [256]
               const float* __restrict__ Wh_w,  // [256, 64]
               const float* __restrict__ Wh_b,  // [256]
               const float* __restrict__ fc_w,  // [64]
               const float* __restrict__ fc_b,  // [1]
               float* __restrict__ out)         // [B]
{
    __shared__ short a_buf[2][3][64][8];   // 6144 B
    __shared__ float red[4][16];

    const int tid  = threadIdx.x;
    const int l    = tid & 63;
    const int wv   = tid >> 6;       // wave: units [wv*16, wv*16+16) x 4 gates
    const int lrow = l & 15;
    const int lhi  = l >> 4;
    const int row0 = blockIdx.x * TILE_B;

    // ---- W^T B-fragments (bf16, log2e pre-scaled): 12 frags = 48 VGPR ----
    bf16x8 w_hi[4][3];
    #pragma unroll
    for (int g = 0; g < 4; ++g) {
        const int col = g * 64 + wv * 16 + lrow;
        const float scale = (g == 2) ? LOG2E2 : LOG2E;   // gates i,f,g,o
        #pragma unroll
        for (int s = 0; s < 3; ++s) {
            bf16x8 hi;
            #pragma unroll
            for (int j = 0; j < 8; ++j) {
                const int k = s * 32 + lhi * 8 + j;
                float val;
                if (k < F_IN)           val = Wx_w[col * F_IN + k];
                else if (k < 89)        val = Wh_w[col * H_DIM + (k - F_IN)];
                else if (k == 89)       val = Wx_b[col] + Wh_b[col];   // fused bias
                else                    val = 0.0f;
                hi[j] = f2bf(val * scale);
            }
            w_hi[g][s] = hi;
        }
    }

    // ---- init a_buf: zeros, bias-one at k==89 (both buffers) ----
    for (int idx = tid; idx < 2 * 3 * 64 * 8; idx += NTHR) {
        const int j    = idx & 7;
        const int lane = (idx >> 3) & 63;
        const int s    = (idx >> 9) % 3;
        const int k    = s * 32 + (lane >> 4) * 8 + j;
        ((short*)a_buf)[idx] = (k == 89) ? (short)0x3F80 : (short)0;
    }
    __syncthreads();

    // ---- per-thread x slot mapping (constant across steps) ----
    const int xrow0 = tid / F_IN,          xf0 = tid % F_IN;           // e0 = tid (<400)
    const int xrow1 = (tid + 256) / F_IN,  xf1 = (tid + 256) % F_IN;   // e1 iff tid<144
    const float* xq0 = x + (size_t)(row0 + xrow0) * TSTEPS * F_IN + xf0;
    const float* xq1 = x + (size_t)(row0 + (tid < 144 ? xrow1 : 0)) * TSTEPS * F_IN + xf1;
    const int xoff0 = ((xrow0 | ((xf0 >> 3) << 4)) * 8) + (xf0 & 7);
    const int xoff1 = ((xrow1 | ((xf1 >> 3) << 4)) * 8) + (xf1 & 7);
    short* const abase = &a_buf[0][0][0][0];

    // x[t=0] into buffer 0
    abase[xoff0] = f2bf(xq0[0]);
    if (tid < 144) abase[xoff1] = f2bf(xq1[0]);
    __syncthreads();

    // advance prefetch pointers to t=1
    xq0 += F_IN;
    xq1 += F_IN;

    // ---- h-write slot mapping (constant): k = 25 + unit ----
    const int unit  = wv * 16 + lrow;
    const int kh    = F_IN + unit;
    const int sh    = kh >> 5;
    const int hbank = ((kh >> 3) & 3) << 4;
    const int jh    = kh & 7;

    const float fcw = fc_w[unit];
    float c[4]  = {0.f, 0.f, 0.f, 0.f};
    float hq[4] = {0.f, 0.f, 0.f, 0.f};

    const f32x4 czero = {0.f, 0.f, 0.f, 0.f};

    // One step; DO_X folds at compile time (true for all but the last step).
    auto step = [&](int t, bool DO_X) {
        const int p  = t & 1;
        const int pn = p ^ 1;

        // A fragments (conflict-free b128, broadcast across waves)
        bf16x8 a0 = *(const bf16x8*)&a_buf[p][0][l][0];
        bf16x8 a1 = *(const bf16x8*)&a_buf[p][1][l][0];
        bf16x8 a2 = *(const bf16x8*)&a_buf[p][2][l][0];

        // prefetch x[t+1]: ISSUE here, CONSUME at step end (proven placement)
        float xv0 = 0.f, xv1 = 0.f;
        if (DO_X) {
            xv0 = xq0[0];
            if (tid < 144) xv1 = xq1[0];
            xq0 += F_IN;
            xq1 += F_IN;
        }

        // z' = v @ W'^T, 12 MFMAs, 4 independent chains
        f32x4 acc0, acc1, acc2, acc3;
        acc0 = __builtin_amdgcn_mfma_f32_16x16x32_bf16(a0, w_hi[0][0], czero, 0, 0, 0);
        acc1 = __builtin_amdgcn_mfma_f32_16x16x32_bf16(a0, w_hi[1][0], czero, 0, 0, 0);
        acc2 = __builtin_amdgcn_mfma_f32_16x16x32_bf16(a0, w_hi[2][0], czero, 0, 0, 0);
        acc3 = __builtin_amdgcn_mfma_f32_16x16x32_bf16(a0, w_hi[3][0], czero, 0, 0, 0);

        acc0 = __builtin_amdgcn_mfma_f32_16x16x32_bf16(a1, w_hi[0][1], acc0, 0, 0, 0);
        acc1 = __builtin_amdgcn_mfma_f32_16x16x32_bf16(a1, w_hi[1][1], acc1, 0, 0, 0);
        acc2 = __builtin_amdgcn_mfma_f32_16x16x32_bf16(a1, w_hi[2][1], acc2, 0, 0, 0);
        acc3 = __builtin_amdgcn_mfma_f32_16x16x32_bf16(a1, w_hi[3][1], acc3, 0, 0, 0);

        acc0 = __builtin_amdgcn_mfma_f32_16x16x32_bf16(a2, w_hi[0][2], acc0, 0, 0, 0);
        acc1 = __builtin_amdgcn_mfma_f32_16x16x32_bf16(a2, w_hi[1][2], acc1, 0, 0, 0);
        acc2 = __builtin_amdgcn_mfma_f32_16x16x32_bf16(a2, w_hi[2][2], acc2, 0, 0, 0);
        acc3 = __builtin_amdgcn_mfma_f32_16x16x32_bf16(a2, w_hi[3][2], acc3, 0, 0, 0);

        // ---- 4 cells; 20 exp + 3 batched rcp per thread ----
        const float ei0 = exp2_neg(acc0[0]), ei1 = exp2_neg(acc0[1]),
                    ei2 = exp2_neg(acc0[2]), ei3 = exp2_neg(acc0[3]);
        const float ef0 = exp2_neg(acc1[0]), ef1 = exp2_neg(acc1[1]),
                    ef2 = exp2_neg(acc1[2]), ef3 = exp2_neg(acc1[3]);
        const float eg0 = exp2_negabs(acc2[0]), eg1 = exp2_negabs(acc2[1]),
                    eg2 = exp2_negabs(acc2[2]), eg3 = exp2_negabs(acc2[3]);
        const float eo0 = exp2_neg(acc3[0]), eo1 = exp2_neg(acc3[1]),
                    eo2 = exp2_neg(acc3[2]), eo3 = exp2_neg(acc3[3]);

        const float A0 = (1.f + ei0) * (1.f + eg0), A1 = (1.f + ei1) * (1.f + eg1),
                    A2 = (1.f + ei2) * (1.f + eg2), A3 = (1.f + ei3) * (1.f + eg3);
        float iA0, iA1, iA2, iA3;
        inv4(A0, A1, A2, A3, iA0, iA1, iA2, iA3);
        float f0, f1, f2, f3;
        inv4(1.f + ef0, 1.f + ef1, 1.f + ef2, 1.f + ef3, f0, f1, f2, f3);

        const float ig0 = copysignf((1.f - eg0) * iA0, acc2[0]);
        const float ig1 = copysignf((1.f - eg1) * iA1, acc2[1]);
        const float ig2 = copysignf((1.f - eg2) * iA2, acc2[2]);
        const float ig3 = copysignf((1.f - eg3) * iA3, acc2[3]);

        const float cn0 = fmaf(c[0], f0, ig0);
        const float cn1 = fmaf(c[1], f1, ig1);
        const float cn2 = fmaf(c[2], f2, ig2);
        const float cn3 = fmaf(c[3], f3, ig3);
        c[0] = cn0; c[1] = cn1; c[2] = cn2; c[3] = cn3;

        const float ec0 = exp2_negabs(cn0 * LOG2E2);
        const float ec1 = exp2_negabs(cn1 * LOG2E2);
        const float ec2 = exp2_negabs(cn2 * LOG2E2);
        const float ec3 = exp2_negabs(cn3 * LOG2E2);
        const float C0 = (1.f + eo0) * (1.f + ec0), C1 = (1.f + eo1) * (1.f + ec1),
                    C2 = (1.f + eo2) * (1.f + ec2), C3 = (1.f + eo3) * (1.f + ec3);
        float iC0, iC1, iC2, iC3;
        inv4(C0, C1, C2, C3, iC0, iC1, iC2, iC3);

        const float h0  = copysignf((1.f - ec0) * iC0, cn0);
        const float h1v = copysignf((1.f - ec1) * iC1, cn1);
        const float h2v = copysignf((1.f - ec2) * iC2, cn2);
        const float h3v = copysignf((1.f - ec3) * iC3, cn3);
        hq[0] = h0; hq[1] = h1v; hq[2] = h2v; hq[3] = h3v;

        // h -> a_buf[pn] (packed cvt, strided b16 stores)
        const unsigned u01 = cvt_pk_bf16(h0, h1v);
        const unsigned u23 = cvt_pk_bf16(h2v, h3v);
        short* const hdst = &a_buf[pn][sh][0][0] + hbank * 8 + lhi * 32 + jh;
        hdst[0]  = (short)(u01 & 0xffffu);
        hdst[8]  = (short)(u01 >> 16);
        hdst[16] = (short)(u23 & 0xffffu);
        hdst[24] = (short)(u23 >> 16);

        // CONSUME x[t+1] -> a_buf[pn] (loads had the whole step to land;
        // vmcnt reaches 0 here, so the __syncthreads drain is free)
        if (DO_X) {
            short* const xdst = abase + pn * (3 * 64 * 8);
            xdst[xoff0] = (short)(cvt_pk_bf16(xv0, xv0) & 0xffffu);
            if (tid < 144) xdst[xoff1] = (short)(cvt_pk_bf16(xv1, xv1) & 0xffffu);
        }
        __syncthreads();
    };

    // steady state branchless (DO_X folds true), last step peeled
    for (int t = 0; t < TSTEPS - 1; ++t) step(t, true);
    step(TSTEPS - 1, false);

    // ---- epilogue: logits = h_last @ fc_w + fc_b ----
    #pragma unroll
    for (int q = 0; q < 4; ++q) {
        float pq = hq[q] * fcw;
        pq += __shfl_xor(pq, 1);
        pq += __shfl_xor(pq, 2);
        pq += __shfl_xor(pq, 4);
        pq += __shfl_xor(pq, 8);
        if (lrow == 0) red[wv][lhi * 4 + q] = pq;
    }
    __syncthreads();
    if (tid < TILE_B) {
        out[row0 + tid] = red[0][tid] + red[1][tid] + red[2][tid] + red[3][tid] + fc_b[0];
    }
}

} // namespace

extern "C" void kernel_launch(void* const* d_in, const int* in_sizes, int n_in,
                              void* d_out, int out_size, void* d_ws, size_t ws_size,
                              hipStream_t stream) {
    const float* x    = (const float*)d_in[0];
    // d_in[1] = mask: all-ones, use_masked_last=False -> unused
    const float* Wx_w = (const float*)d_in[2];
    const float* Wx_b = (const float*)d_in[3];
    const float* Wh_w = (const float*)d_in[4];
    const float* Wh_b = (const float*)d_in[5];
    const float* fc_w = (const float*)d_in[6];
    const float* fc_b = (const float*)d_in[7];
    float* out = (float*)d_out;

    const int B    = out_size;        // 4096
    const int grid = B / TILE_B;      // 256 blocks = 1 per CU

    lstm_mfma<<<grid, NTHR, 0, stream>>>(x, Wx_w, Wx_b, Wh_w, Wh_b, fc_w, fc_b, out);
}